// Round 9
// baseline (239.661 us; speedup 1.0000x reference)
//
#include <hip/hip_runtime.h>
#include <hip/hip_bf16.h>
#include <stdint.h>

#define NB   16384
#define DIN  1024
#define MPAD 16896   /* 16384 + 4*128 : per-domain segments padded to 128 */

typedef __bf16 bf16;
typedef __bf16 v8bf __attribute__((ext_vector_type(8)));
typedef float  v4f  __attribute__((ext_vector_type(4)));
typedef long   v2l  __attribute__((ext_vector_type(2)));
typedef unsigned char u8;

typedef __attribute__((address_space(1))) void* as1_ptr;
typedef __attribute__((address_space(3))) void* as3_ptr;

__device__ __forceinline__ void gl_lds16(const void* g, void* l) {
  __builtin_amdgcn_global_load_lds((as1_ptr)(g), (as3_ptr)(l), 16, 0, 0);
}

__device__ __forceinline__ unsigned short bfbits(float f) {
  bf16 h = (bf16)f;
  return __builtin_bit_cast(unsigned short, h);
}

// pack 2 floats -> 2 fp8 e4m3 bytes (byte0=a, byte1=b)
__device__ __forceinline__ unsigned short pk8(float a, float b) {
  int u = __builtin_amdgcn_cvt_pk_fp8_f32(a, b, 0, false);
  return (unsigned short)(u & 0xffff);
}

// ------------------------------------------------ prep: weight transpose (0..841)
// + histogram partials / perm init / aux net (842..905). No atomics, no init deps.
__global__ __launch_bounds__(256) void k_prep(
    const float* __restrict__ cW1, const float* __restrict__ cW2,
    const float* __restrict__ cW3, const float* __restrict__ dW1,
    const float* __restrict__ dW2, const float* __restrict__ dW3,
    const float* __restrict__ fW1,
    u8* __restrict__ cW1t, u8* __restrict__ cW2t, u8* __restrict__ cW3t,
    u8* __restrict__ dW1t, u8* __restrict__ dW2t, u8* __restrict__ dW3t,
    bf16* __restrict__ fW1t,
    const int* __restrict__ dom, int* __restrict__ partials, int* __restrict__ perm,
    const float* __restrict__ dom_emb, const float* __restrict__ aW1,
    const float* __restrict__ ab1, const float* __restrict__ aW2,
    const float* __restrict__ ab2, float* __restrict__ aux) {
  __shared__ float t[64 * 65];
  int bid = blockIdx.x;
  int tid = threadIdx.x;
  if (bid >= 842) {
    int b2 = bid - 842;                 // 0..63, rows [b2*256, +256)
    int wv = tid >> 6, lane = tid & 63;
    int row = b2 * 256 + tid;
    int d = dom[row];
    int gbase = b2 * 16 + wv * 4;       // 16-row group ids
#pragma unroll
    for (int dd = 0; dd < 4; dd++) {
      unsigned long long m = __ballot(d == dd);
      int q = lane >> 4;
      int cnt = __popcll((m >> (16 * q)) & 0xFFFFull);
      if ((lane & 15) == 0) partials[(gbase + q) * 4 + dd] = cnt;
    }
    for (int j = b2 * 264 + tid; j < b2 * 264 + 264; j += 256)
      if (j < MPAD) perm[j] = -1;
    if (b2 == 0 && tid >= 64 && tid < 68) {
      int dd = tid - 64;
      float a = ab2[0];
      for (int j = 0; j < 32; j++) {
        float s = ab1[j];
        for (int i = 0; i < 16; i++) s += dom_emb[dd * 16 + i] * aW1[i * 32 + j];
        a += fmaxf(s, 0.f) * aW2[j];
      }
      aux[dd] = a;
    }
    return;
  }
  // weight transpose: 15 fp8 matrices (KxN fp32 -> NxK fp8, x16) + fW1 bf16
  const float* src; u8* dst; int K, N, tile; bool isf = false;
  if (bid < 640) {
    K = 1024; N = 512; int m = bid >> 7; tile = bid & 127;
    src = m == 0 ? cW1 : dW1 + (size_t)(m - 1) * 524288;
    dst = m == 0 ? cW1t : dW1t + (size_t)(m - 1) * 524288;
  } else if (bid < 800) {
    K = 512; N = 256; int m = (bid - 640) >> 5; tile = (bid - 640) & 31;
    src = m == 0 ? cW2 : dW2 + (size_t)(m - 1) * 131072;
    dst = m == 0 ? cW2t : dW2t + (size_t)(m - 1) * 131072;
  } else if (bid < 840) {
    K = 256; N = 128; int m = (bid - 800) >> 3; tile = (bid - 800) & 7;
    src = m == 0 ? cW3 : dW3 + (size_t)(m - 1) * 32768;
    dst = m == 0 ? cW3t : dW3t + (size_t)(m - 1) * 32768;
  } else {
    K = 128; N = 64; tile = bid - 840; src = fW1; dst = nullptr; isf = true;
  }
  int ntn = N >> 6;
  int k0 = (tile / ntn) << 6, n0 = (tile % ntn) << 6;
  int r = tid >> 2, c4 = (tid & 3) << 4;
#pragma unroll
  for (int j4 = 0; j4 < 4; j4++) {
    float4 v = *(const float4*)(src + (size_t)(k0 + r) * N + n0 + c4 + j4 * 4);
    t[r * 65 + c4 + j4 * 4 + 0] = v.x;
    t[r * 65 + c4 + j4 * 4 + 1] = v.y;
    t[r * 65 + c4 + j4 * 4 + 2] = v.z;
    t[r * 65 + c4 + j4 * 4 + 3] = v.w;
  }
  __syncthreads();
  int n = tid >> 2, kc = (tid & 3) << 4;
  if (!isf) {
#pragma unroll
    for (int j4 = 0; j4 < 4; j4++) {
      float v0 = t[(kc + j4 * 4 + 0) * 65 + n] * 16.f;
      float v1 = t[(kc + j4 * 4 + 1) * 65 + n] * 16.f;
      float v2 = t[(kc + j4 * 4 + 2) * 65 + n] * 16.f;
      float v3 = t[(kc + j4 * 4 + 3) * 65 + n] * 16.f;
      int u = __builtin_amdgcn_cvt_pk_fp8_f32(v0, v1, 0, false);
      u = __builtin_amdgcn_cvt_pk_fp8_f32(v2, v3, u, true);
      *(unsigned int*)(dst + (size_t)(n0 + n) * K + k0 + kc + j4 * 4) = (unsigned int)u;
    }
  } else {
#pragma unroll
    for (int j4 = 0; j4 < 4; j4++) {
      ushort4 o;
      o.x = bfbits(t[(kc + j4 * 4 + 0) * 65 + n]);
      o.y = bfbits(t[(kc + j4 * 4 + 1) * 65 + n]);
      o.z = bfbits(t[(kc + j4 * 4 + 2) * 65 + n]);
      o.w = bfbits(t[(kc + j4 * 4 + 3) * 65 + n]);
      *(ushort4*)(fW1t + (size_t)(n0 + n) * K + k0 + kc + j4 * 4) = o;
    }
  }
}

// ------------------------------------------------ sort + layernorm fused
__global__ __launch_bounds__(256) void k_sortln(
    const float* __restrict__ x, const int* __restrict__ dom,
    const int* __restrict__ partials,
    const float* __restrict__ pn_w, const float* __restrict__ pn_b,
    int* __restrict__ pstart_g, int* __restrict__ perm, u8* __restrict__ norm) {
  __shared__ int totL[4], preL[4];
  __shared__ int posL[16];
  const int tid = threadIdx.x, wv = tid >> 6, lane = tid & 63;
  const int B = blockIdx.x;            // rows [B*16, +16)
  int tot = 0, pre = 0;
  for (int g = lane; g < 1024; g += 64) {
    int v = partials[g * 4 + wv];
    tot += v;
    if (g < B) pre += v;
  }
#pragma unroll
  for (int o = 32; o; o >>= 1) {
    tot += __shfl_xor(tot, o, 64);
    pre += __shfl_xor(pre, o, 64);
  }
  if (lane == 0) { totL[wv] = tot; preL[wv] = pre; }
  __syncthreads();
  const int p1 = (totL[0] + 127) & ~127;
  const int p2 = p1 + ((totL[1] + 127) & ~127);
  const int p3 = p2 + ((totL[2] + 127) & ~127);
  if (B == 0 && tid < 5) {
    int ps0 = (tid == 0) ? 0 : (tid == 1 ? p1 : (tid == 2 ? p2 : (tid == 3 ? p3
              : p3 + ((totL[3] + 127) & ~127))));
    pstart_g[tid] = ps0;
  }
  if (wv == 0 && lane < 16) {
    int row = B * 16 + lane;
    int d = dom[row];
    unsigned long long ltm = (1ull << lane) - 1ull;
    int pstA[4] = {0, p1, p2, p3};
    int pos = 0;
#pragma unroll
    for (int dd = 0; dd < 4; dd++) {
      unsigned long long m = __ballot(d == dd);
      if (d == dd) pos = pstA[dd] + preL[dd] + (int)__popcll(m & ltm);
    }
    posL[lane] = pos;
    perm[pos] = row;
  }
  __syncthreads();
  for (int i = 0; i < 4; i++) {
    int ridx = wv * 4 + i;
    int r = B * 16 + ridx;
    const float* xr = x + (size_t)r * DIN;
    float4 v[4];
#pragma unroll
    for (int g = 0; g < 4; g++) v[g] = *(const float4*)(xr + g * 256 + lane * 4);
    float s = 0.f;
#pragma unroll
    for (int g = 0; g < 4; g++) s += v[g].x + v[g].y + v[g].z + v[g].w;
#pragma unroll
    for (int o = 32; o; o >>= 1) s += __shfl_xor(s, o, 64);
    float mean = s * (1.f / 1024.f);
    float q = 0.f;
#pragma unroll
    for (int g = 0; g < 4; g++) {
      float a = v[g].x - mean, b = v[g].y - mean, c = v[g].z - mean, e = v[g].w - mean;
      q += a * a + b * b + c * c + e * e;
    }
#pragma unroll
    for (int o = 32; o; o >>= 1) q += __shfl_xor(q, o, 64);
    float rstd = rsqrtf(q * (1.f / 1024.f) + 1e-5f);
    int d = dom[r];
    int pos = posL[ridx];
    const float* pw = pn_w + (size_t)d * DIN;
    const float* pb = pn_b + (size_t)d * DIN;
    u8* orow = norm + (size_t)pos * DIN;
#pragma unroll
    for (int g = 0; g < 4; g++) {
      float4 w4 = *(const float4*)(pw + g * 256 + lane * 4);
      float4 b4 = *(const float4*)(pb + g * 256 + lane * 4);
      float f0 = (v[g].x - mean) * rstd * w4.x + b4.x;
      float f1 = (v[g].y - mean) * rstd * w4.y + b4.y;
      float f2 = (v[g].z - mean) * rstd * w4.z + b4.z;
      float f3 = (v[g].w - mean) * rstd * w4.w + b4.w;
      int u = __builtin_amdgcn_cvt_pk_fp8_f32(f0, f1, 0, false);
      u = __builtin_amdgcn_cvt_pk_fp8_f32(f2, f3, u, true);
      *(unsigned int*)(orow + g * 256 + lane * 4) = (unsigned int)u;
    }
  }
}

// ------------------------------------------------ fused center|domain fp8 GEMM (L1, L2)
// M-tile 64, N-tile 256, BK 128. Doubles MFMA work per barrier pair vs N128
// (same proven fragment/swizzle geometry; only row extents changed).
__global__ __launch_bounds__(256) void k_gemm(const u8* __restrict__ A, int lda,
                                              int aoffc, int aoffd,
                                              const u8* __restrict__ cWt,
                                              const u8* __restrict__ dWt,
                                              const float* __restrict__ cb,
                                              const float* __restrict__ db,
                                              u8* __restrict__ C, int Nh, int Kd,
                                              int relu, const int* __restrict__ pstart,
                                              int lognct) {
  __shared__ __align__(16) u8 Al[64 * 128];    // 8 KB
  __shared__ __align__(16) u8 Bl[256 * 128];   // 32 KB
  const int tid = threadIdx.x;
  const int wv = tid >> 6, lane = tid & 63;
  const int nct = 1 << lognct;
  // XCD swizzle: col-tiles of one row-tile share l&7 -> same XCD L2.
  int l = blockIdx.x;
  int t = l >> 3;
  int ct = t & (nct - 1);
  int rt = ((t >> lognct) << 3) | (l & 7);   // 264 row-tiles, 264%8==0
  const int row0 = rt * 64;
  const int d = (row0 >= pstart[1]) + (row0 >= pstart[2]) + (row0 >= pstart[3]);
  const int n0 = ct * 256;
  const bool isd = (n0 >= Nh);
  const u8* Wt = isd ? dWt + ((size_t)d * Nh + (n0 - Nh)) * Kd : cWt + (size_t)n0 * Kd;
  const float* bias = isd ? db + d * Nh + (n0 - Nh) : cb + n0;
  const int aoff = isd ? aoffd : aoffc;
  const u8* Ab = A + (size_t)row0 * lda + aoff;

  v4f acc[2][8];
#pragma unroll
  for (int i = 0; i < 2; i++)
#pragma unroll
    for (int j = 0; j < 8; j++) acc[i][j] = v4f{0.f, 0.f, 0.f, 0.f};

  const int wm = (wv >> 1) * 32, wn = (wv & 1) * 128;
  const int mrow = lane & 15, quad = lane >> 4;
  const int lrow = lane >> 3;   // loader: 8 rows per instr
  const int lchk = lane & 7;    // loader: 8 chunks of 16B per row
  const int ldc = 2 * Nh;

  for (int kt = 0; kt < Kd; kt += 128) {
#pragma unroll
    for (int p = 0; p < 2; p++) {          // A: wave rows [wv*16, +16)
      int rbase = wv * 16 + p * 8;
      int r = rbase + lrow;
      int jg = lchk ^ (r & 7);
      gl_lds16(Ab + (size_t)r * lda + kt + jg * 16, &Al[rbase * 128]);
    }
#pragma unroll
    for (int p = 0; p < 8; p++) {          // B: wave rows [wv*64, +64)
      int rbase = wv * 64 + p * 8;
      int r = rbase + lrow;
      int jg = lchk ^ (r & 7);
      gl_lds16(Wt + (size_t)r * Kd + kt + jg * 16, &Bl[rbase * 128]);
    }
    __syncthreads();
#pragma unroll
    for (int sp = 0; sp < 2; sp++) {
      v2l af[2], bfr[8];
#pragma unroll
      for (int mi = 0; mi < 2; mi++) {
        int m = wm + mi * 16 + mrow;
        int c = (sp * 4 + quad) ^ (m & 7);
        af[mi] = *(const v2l*)&Al[m * 128 + c * 16];
      }
#pragma unroll
      for (int ni = 0; ni < 8; ni++) {
        int n = wn + ni * 16 + mrow;
        int c = (sp * 4 + quad) ^ (n & 7);
        bfr[ni] = *(const v2l*)&Bl[n * 128 + c * 16];
      }
#pragma unroll
      for (int mi = 0; mi < 2; mi++)
#pragma unroll
        for (int ni = 0; ni < 8; ni++)
          acc[mi][ni] =
              __builtin_amdgcn_mfma_f32_16x16x32_fp8_fp8(af[mi].x, bfr[ni].x, acc[mi][ni], 0, 0, 0);
#pragma unroll
      for (int mi = 0; mi < 2; mi++)
#pragma unroll
        for (int ni = 0; ni < 8; ni++)
          acc[mi][ni] =
              __builtin_amdgcn_mfma_f32_16x16x32_fp8_fp8(af[mi].y, bfr[ni].y, acc[mi][ni], 0, 0, 0);
    }
    __syncthreads();
  }

  float bv[8];
#pragma unroll
  for (int ni = 0; ni < 8; ni++) bv[ni] = bias[wn + ni * 16 + mrow];
#pragma unroll
  for (int mi = 0; mi < 2; mi++) {
    int growb = row0 + wm + mi * 16 + quad * 4;
#pragma unroll
    for (int ni = 0; ni < 8; ni++) {
      int gcol = n0 + wn + ni * 16 + mrow;
#pragma unroll
      for (int r2 = 0; r2 < 4; r2++) {
        float v = acc[mi][ni][r2] * 0.0625f + bv[ni];
        if (relu) v = fmaxf(v, 0.f);
        float g = __shfl_xor(v, 1, 64);
        if (!(mrow & 1))
          *(unsigned short*)(C + (size_t)(growb + r2) * ldc + gcol) = pk8(v, g);
      }
    }
  }
}

// ------------------------------------------------ L3 fp8 GEMM + bf16 MFMA head [R5-proven]
__global__ __launch_bounds__(256) void k_gemm3(const u8* __restrict__ A,
                                               const u8* __restrict__ cW3t,
                                               const u8* __restrict__ dW3t,
                                               const float* __restrict__ cb3,
                                               const float* __restrict__ db3,
                                               const bf16* __restrict__ fW1t,
                                               const float* __restrict__ fb1,
                                               const float* __restrict__ fW2,
                                               const float* __restrict__ fb2,
                                               const int* __restrict__ perm,
                                               const int* __restrict__ pstart,
                                               const float* __restrict__ aux,
                                               float* __restrict__ out) {
  __shared__ __align__(16) u8 Al[64 * 128];        // 8 KB
  __shared__ __align__(16) u8 Bl[128 * 128];       // 16 KB
  __shared__ __align__(16) bf16 fusedL[64 * 128];  // 16 KB, XOR-swizzled 8-elt chunks
  __shared__ __align__(16) bf16 fwB[64 * 128];     // 16 KB, XOR-swizzled 8-elt chunks
  const int tid = threadIdx.x, wv = tid >> 6, lane = tid & 63;
  const int row0 = blockIdx.x * 64;
  const int d = (row0 >= pstart[1]) + (row0 >= pstart[2]) + (row0 >= pstart[3]);
  const u8* Ab = A + (size_t)row0 * 512;
  const int mrow = lane & 15, quad = lane >> 4;
  const int lrow = lane >> 3, lchk = lane & 7;
  const int wm = (wv >> 1) * 32, wn = (wv & 1) * 64;

  {
    int c = lane & 15, rsub = lane >> 4;
#pragma unroll
    for (int p = 0; p < 4; p++) {
      int rbase = wv * 16 + p * 4;
      int row = rbase + rsub;
      int g = (c & 8) | ((c ^ row) & 7);
      gl_lds16(fW1t + row * 128 + g * 8, &fwB[rbase * 128]);
    }
  }

  v4f accC[2][4], accD[2][4];
#pragma unroll
  for (int i = 0; i < 2; i++)
#pragma unroll
    for (int j = 0; j < 4; j++) { accC[i][j] = v4f{0.f,0.f,0.f,0.f}; accD[i][j] = v4f{0.f,0.f,0.f,0.f}; }

#pragma unroll
  for (int ph = 0; ph < 2; ph++) {
    const u8* Wt = ph ? dW3t + (size_t)d * 32768 : cW3t;
    const int aoff = ph * 256;
    for (int kt = 0; kt < 256; kt += 128) {
#pragma unroll
      for (int p = 0; p < 2; p++) {        // A: 64 rows
        int rbase = wv * 16 + p * 8;
        int r = rbase + lrow;
        int jg = lchk ^ (r & 7);
        gl_lds16(Ab + (size_t)r * 512 + aoff + kt + jg * 16, &Al[rbase * 128]);
      }
#pragma unroll
      for (int p = 0; p < 4; p++) {        // B: 128 rows
        int rbase = wv * 32 + p * 8;
        int r = rbase + lrow;
        int jg = lchk ^ (r & 7);
        gl_lds16(Wt + (size_t)r * 256 + kt + jg * 16, &Bl[rbase * 128]);
      }
      __syncthreads();
#pragma unroll
      for (int sp = 0; sp < 2; sp++) {
        v2l af[2], bfr[4];
#pragma unroll
        for (int mi = 0; mi < 2; mi++) {
          int m = wm + mi * 16 + mrow;
          int c = (sp * 4 + quad) ^ (m & 7);
          af[mi] = *(const v2l*)&Al[m * 128 + c * 16];
        }
#pragma unroll
        for (int ni = 0; ni < 4; ni++) {
          int n = wn + ni * 16 + mrow;
          int c = (sp * 4 + quad) ^ (n & 7);
          bfr[ni] = *(const v2l*)&Bl[n * 128 + c * 16];
        }
        if (ph == 0) {
#pragma unroll
          for (int mi = 0; mi < 2; mi++)
#pragma unroll
            for (int ni = 0; ni < 4; ni++) {
              accC[mi][ni] = __builtin_amdgcn_mfma_f32_16x16x32_fp8_fp8(af[mi].x, bfr[ni].x, accC[mi][ni], 0, 0, 0);
              accC[mi][ni] = __builtin_amdgcn_mfma_f32_16x16x32_fp8_fp8(af[mi].y, bfr[ni].y, accC[mi][ni], 0, 0, 0);
            }
        } else {
#pragma unroll
          for (int mi = 0; mi < 2; mi++)
#pragma unroll
            for (int ni = 0; ni < 4; ni++) {
              accD[mi][ni] = __builtin_amdgcn_mfma_f32_16x16x32_fp8_fp8(af[mi].x, bfr[ni].x, accD[mi][ni], 0, 0, 0);
              accD[mi][ni] = __builtin_amdgcn_mfma_f32_16x16x32_fp8_fp8(af[mi].y, bfr[ni].y, accD[mi][ni], 0, 0, 0);
            }
        }
      }
      __syncthreads();
    }
  }

#pragma unroll
  for (int mi = 0; mi < 2; mi++) {
    int rowb = wm + mi * 16 + quad * 4;
#pragma unroll
    for (int ni = 0; ni < 4; ni++) {
      int col = wn + ni * 16 + mrow;
      float cbv = cb3[col];
      float dbv = db3[d * 128 + col];
      int jc = col >> 3, coff = col & 7;
#pragma unroll
      for (int r2 = 0; r2 < 4; r2++) {
        int rr = rowb + r2;
        float f = (accC[mi][ni][r2] * 0.0625f + cbv) * tanhf(accD[mi][ni][r2] * 0.0625f + dbv);
        int cs = (jc & 8) | ((jc ^ rr) & 7);
        fusedL[rr * 128 + cs * 8 + coff] = (bf16)f;
      }
    }
  }
  __syncthreads();

  float fb1v[4], fW2v[4];
#pragma unroll
  for (int nt = 0; nt < 4; nt++) {
    int col = nt * 16 + mrow;
    fb1v[nt] = fb1[col];
    fW2v[nt] = fW2[col];
  }
  v4f hacc[4];
#pragma unroll
  for (int nt = 0; nt < 4; nt++) hacc[nt] = v4f{0.f, 0.f, 0.f, 0.f};
  const int m = wv * 16 + mrow;
#pragma unroll
  for (int s = 0; s < 4; s++) {
    int j = s * 4 + quad;
    int ca = (j & 8) | ((j ^ m) & 7);
    v8bf af = *(const v8bf*)&fusedL[m * 128 + ca * 8];
#pragma unroll
    for (int nt = 0; nt < 4; nt++) {
      int n = nt * 16 + mrow;
      int cbk = (j & 8) | ((j ^ n) & 7);
      v8bf bfr = *(const v8bf*)&fwB[n * 128 + cbk * 8];
      hacc[nt] = __builtin_amdgcn_mfma_f32_16x16x32_bf16(af, bfr, hacc[nt], 0, 0, 0);
    }
  }
  float ys[4];
#pragma unroll
  for (int r2 = 0; r2 < 4; r2++) {
    float s = 0.f;
#pragma unroll
    for (int nt = 0; nt < 4; nt++) s += fmaxf(hacc[nt][r2] + fb1v[nt], 0.f) * fW2v[nt];
    ys[r2] = s;
  }
#pragma unroll
  for (int o = 1; o < 16; o <<= 1)
#pragma unroll
    for (int r2 = 0; r2 < 4; r2++) ys[r2] += __shfl_xor(ys[r2], o, 64);
  if (mrow == 0) {
    const float addc = fb2[0] + aux[d];
#pragma unroll
    for (int r2 = 0; r2 < 4; r2++) {
      int prow = row0 + wv * 16 + quad * 4 + r2;
      int orig = perm[prow];
      if (orig >= 0) out[orig] = 1.f / (1.f + expf(-(ys[r2] + addc)));
    }
  }
}

// ------------------------------------------------ launch
extern "C" void kernel_launch(void* const* d_in, const int* in_sizes, int n_in,
                              void* d_out, int out_size, void* d_ws, size_t ws_size,
                              hipStream_t stream) {
  (void)in_sizes; (void)n_in; (void)out_size; (void)ws_size;
  const float* x      = (const float*)d_in[0];
  const int*   dom    = (const int*)d_in[1];
  const float* pn_w   = (const float*)d_in[2];
  const float* pn_b   = (const float*)d_in[3];
  const float* cW1    = (const float*)d_in[4];
  const float* cb1    = (const float*)d_in[5];
  const float* cW2    = (const float*)d_in[6];
  const float* cb2    = (const float*)d_in[7];
  const float* cW3    = (const float*)d_in[8];
  const float* cb3    = (const float*)d_in[9];
  const float* dW1    = (const float*)d_in[10];
  const float* db1    = (const float*)d_in[11];
  const float* dW2    = (const float*)d_in[12];
  const float* db2    = (const float*)d_in[13];
  const float* dW3    = (const float*)d_in[14];
  const float* db3    = (const float*)d_in[15];
  const float* fW1    = (const float*)d_in[16];
  const float* fb1    = (const float*)d_in[17];
  const float* fW2    = (const float*)d_in[18];
  const float* fb2    = (const float*)d_in[19];
  const float* demb   = (const float*)d_in[20];
  const float* aW1    = (const float*)d_in[21];
  const float* ab1    = (const float*)d_in[22];
  const float* aW2    = (const float*)d_in[23];
  const float* ab2    = (const float*)d_in[24];
  float* out = (float*)d_out;

  char* w = (char*)d_ws;
  int*   pstart  = (int*)(w + 32);      // [5]
  float* aux     = (float*)(w + 64);    // [4]
  int*   perm    = (int*)(w + 256);                    // [MPAD] -> 67840
  int*   partials= (int*)(w + 67840);                  // [1024*4] -> 84224
  u8*    bufA    = (u8*)(w + 133376);                  // norm MPADx1024 fp8, then h2 MPADx512
  u8*    bufB    = (u8*)(w + 17434880);                // h1 MPADx1024 fp8
  u8*    cW1t    = (u8*)(w + 34736384);
  u8*    cW2t    = (u8*)(w + 35260672);
  u8*    cW3t    = (u8*)(w + 35391744);
  u8*    dW1t    = (u8*)(w + 35424512);
  u8*    dW2t    = (u8*)(w + 37521664);
  u8*    dW3t    = (u8*)(w + 38045952);
  bf16*  fW1t    = (bf16*)(w + 38177024);              // 64x128 bf16 -> end 38193408

  // prep: weight transpose + hist partials + perm init + aux
  k_prep<<<906, 256, 0, stream>>>(cW1, cW2, cW3, dW1, dW2, dW3, fW1,
                                  cW1t, cW2t, cW3t, dW1t, dW2t, dW3t, fW1t,
                                  dom, partials, perm,
                                  demb, aW1, ab1, aW2, ab2, aux);
  // sort + layernorm fused
  k_sortln<<<1024, 256, 0, stream>>>(x, dom, partials, pn_w, pn_b,
                                     pstart, perm, bufA);

  // L1: norm(bufA) -> h1(bufB) : K=1024, Nh=512, relu, 4 col tiles of 256
  k_gemm<<<1056, 256, 0, stream>>>(bufA, 1024, 0, 0, cW1t, dW1t, cb1, db1,
                                   bufB, 512, 1024, 1, pstart, 2);
  // L2: h1(bufB) -> h2(bufA) : K=512, Nh=256, relu, 2 col tiles of 256
  k_gemm<<<528, 256, 0, stream>>>(bufB, 1024, 0, 512, cW2t, dW2t, cb2, db2,
                                  bufA, 256, 512, 1, pstart, 1);
  // L3 + head fused: h2(bufA) -> out
  k_gemm3<<<264, 256, 0, stream>>>(bufA, cW3t, dW3t, cb3, db3, fW1t,
                                   fb1, fW2, fb2, perm, pstart, aux, out);
}

// Round 10
// 223.244 us; speedup vs baseline: 1.0735x; 1.0735x over previous
//
#include <hip/hip_runtime.h>
#include <hip/hip_bf16.h>
#include <stdint.h>

#define NB   16384
#define DIN  1024
#define MPAD 16896   /* 16384 + 4*128 : per-domain segments padded to 128 */

typedef __bf16 bf16;
typedef __bf16 v8bf __attribute__((ext_vector_type(8)));
typedef float  v4f  __attribute__((ext_vector_type(4)));
typedef long   v2l  __attribute__((ext_vector_type(2)));
typedef unsigned char u8;

typedef __attribute__((address_space(1))) void* as1_ptr;
typedef __attribute__((address_space(3))) void* as3_ptr;

__device__ __forceinline__ void gl_lds16(const void* g, void* l) {
  __builtin_amdgcn_global_load_lds((as1_ptr)(g), (as3_ptr)(l), 16, 0, 0);
}

__device__ __forceinline__ unsigned short bfbits(float f) {
  bf16 h = (bf16)f;
  return __builtin_bit_cast(unsigned short, h);
}

// pack 2 floats -> 2 fp8 e4m3 bytes (byte0=a, byte1=b)
__device__ __forceinline__ unsigned short pk8(float a, float b) {
  int u = __builtin_amdgcn_cvt_pk_fp8_f32(a, b, 0, false);
  return (unsigned short)(u & 0xffff);
}

// ------------------------------------------------ prep: weight transpose (0..841)
// + histogram partials / perm init / aux net (842..905). No atomics, no init deps.
__global__ __launch_bounds__(256) void k_prep(
    const float* __restrict__ cW1, const float* __restrict__ cW2,
    const float* __restrict__ cW3, const float* __restrict__ dW1,
    const float* __restrict__ dW2, const float* __restrict__ dW3,
    const float* __restrict__ fW1,
    u8* __restrict__ cW1t, u8* __restrict__ cW2t, u8* __restrict__ cW3t,
    u8* __restrict__ dW1t, u8* __restrict__ dW2t, u8* __restrict__ dW3t,
    bf16* __restrict__ fW1t,
    const int* __restrict__ dom, int* __restrict__ partials, int* __restrict__ perm,
    const float* __restrict__ dom_emb, const float* __restrict__ aW1,
    const float* __restrict__ ab1, const float* __restrict__ aW2,
    const float* __restrict__ ab2, float* __restrict__ aux) {
  __shared__ float t[64 * 65];
  int bid = blockIdx.x;
  int tid = threadIdx.x;
  if (bid >= 842) {
    int b2 = bid - 842;                 // 0..63, rows [b2*256, +256)
    int wv = tid >> 6, lane = tid & 63;
    int row = b2 * 256 + tid;
    int d = dom[row];
    int gbase = b2 * 16 + wv * 4;       // 16-row group ids
#pragma unroll
    for (int dd = 0; dd < 4; dd++) {
      unsigned long long m = __ballot(d == dd);
      int q = lane >> 4;
      int cnt = __popcll((m >> (16 * q)) & 0xFFFFull);
      if ((lane & 15) == 0) partials[(gbase + q) * 4 + dd] = cnt;
    }
    for (int j = b2 * 264 + tid; j < b2 * 264 + 264; j += 256)
      if (j < MPAD) perm[j] = -1;
    if (b2 == 0 && tid >= 64 && tid < 68) {
      int dd = tid - 64;
      float a = ab2[0];
      for (int j = 0; j < 32; j++) {
        float s = ab1[j];
        for (int i = 0; i < 16; i++) s += dom_emb[dd * 16 + i] * aW1[i * 32 + j];
        a += fmaxf(s, 0.f) * aW2[j];
      }
      aux[dd] = a;
    }
    return;
  }
  // weight transpose: 15 fp8 matrices (KxN fp32 -> NxK fp8, x16) + fW1 bf16
  const float* src; u8* dst; int K, N, tile; bool isf = false;
  if (bid < 640) {
    K = 1024; N = 512; int m = bid >> 7; tile = bid & 127;
    src = m == 0 ? cW1 : dW1 + (size_t)(m - 1) * 524288;
    dst = m == 0 ? cW1t : dW1t + (size_t)(m - 1) * 524288;
  } else if (bid < 800) {
    K = 512; N = 256; int m = (bid - 640) >> 5; tile = (bid - 640) & 31;
    src = m == 0 ? cW2 : dW2 + (size_t)(m - 1) * 131072;
    dst = m == 0 ? cW2t : dW2t + (size_t)(m - 1) * 131072;
  } else if (bid < 840) {
    K = 256; N = 128; int m = (bid - 800) >> 3; tile = (bid - 800) & 7;
    src = m == 0 ? cW3 : dW3 + (size_t)(m - 1) * 32768;
    dst = m == 0 ? cW3t : dW3t + (size_t)(m - 1) * 32768;
  } else {
    K = 128; N = 64; tile = bid - 840; src = fW1; dst = nullptr; isf = true;
  }
  int ntn = N >> 6;
  int k0 = (tile / ntn) << 6, n0 = (tile % ntn) << 6;
  int r = tid >> 2, c4 = (tid & 3) << 4;
#pragma unroll
  for (int j4 = 0; j4 < 4; j4++) {
    float4 v = *(const float4*)(src + (size_t)(k0 + r) * N + n0 + c4 + j4 * 4);
    t[r * 65 + c4 + j4 * 4 + 0] = v.x;
    t[r * 65 + c4 + j4 * 4 + 1] = v.y;
    t[r * 65 + c4 + j4 * 4 + 2] = v.z;
    t[r * 65 + c4 + j4 * 4 + 3] = v.w;
  }
  __syncthreads();
  int n = tid >> 2, kc = (tid & 3) << 4;
  if (!isf) {
#pragma unroll
    for (int j4 = 0; j4 < 4; j4++) {
      float v0 = t[(kc + j4 * 4 + 0) * 65 + n] * 16.f;
      float v1 = t[(kc + j4 * 4 + 1) * 65 + n] * 16.f;
      float v2 = t[(kc + j4 * 4 + 2) * 65 + n] * 16.f;
      float v3 = t[(kc + j4 * 4 + 3) * 65 + n] * 16.f;
      int u = __builtin_amdgcn_cvt_pk_fp8_f32(v0, v1, 0, false);
      u = __builtin_amdgcn_cvt_pk_fp8_f32(v2, v3, u, true);
      *(unsigned int*)(dst + (size_t)(n0 + n) * K + k0 + kc + j4 * 4) = (unsigned int)u;
    }
  } else {
#pragma unroll
    for (int j4 = 0; j4 < 4; j4++) {
      ushort4 o;
      o.x = bfbits(t[(kc + j4 * 4 + 0) * 65 + n]);
      o.y = bfbits(t[(kc + j4 * 4 + 1) * 65 + n]);
      o.z = bfbits(t[(kc + j4 * 4 + 2) * 65 + n]);
      o.w = bfbits(t[(kc + j4 * 4 + 3) * 65 + n]);
      *(ushort4*)(fW1t + (size_t)(n0 + n) * K + k0 + kc + j4 * 4) = o;
    }
  }
}

// ------------------------------------------------ sort + layernorm fused
__global__ __launch_bounds__(256) void k_sortln(
    const float* __restrict__ x, const int* __restrict__ dom,
    const int* __restrict__ partials,
    const float* __restrict__ pn_w, const float* __restrict__ pn_b,
    int* __restrict__ pstart_g, int* __restrict__ perm, u8* __restrict__ norm) {
  __shared__ int totL[4], preL[4];
  __shared__ int posL[16];
  const int tid = threadIdx.x, wv = tid >> 6, lane = tid & 63;
  const int B = blockIdx.x;            // rows [B*16, +16)
  int tot = 0, pre = 0;
  for (int g = lane; g < 1024; g += 64) {
    int v = partials[g * 4 + wv];
    tot += v;
    if (g < B) pre += v;
  }
#pragma unroll
  for (int o = 32; o; o >>= 1) {
    tot += __shfl_xor(tot, o, 64);
    pre += __shfl_xor(pre, o, 64);
  }
  if (lane == 0) { totL[wv] = tot; preL[wv] = pre; }
  __syncthreads();
  const int p1 = (totL[0] + 127) & ~127;
  const int p2 = p1 + ((totL[1] + 127) & ~127);
  const int p3 = p2 + ((totL[2] + 127) & ~127);
  if (B == 0 && tid < 5) {
    int ps0 = (tid == 0) ? 0 : (tid == 1 ? p1 : (tid == 2 ? p2 : (tid == 3 ? p3
              : p3 + ((totL[3] + 127) & ~127))));
    pstart_g[tid] = ps0;
  }
  if (wv == 0 && lane < 16) {
    int row = B * 16 + lane;
    int d = dom[row];
    unsigned long long ltm = (1ull << lane) - 1ull;
    int pstA[4] = {0, p1, p2, p3};
    int pos = 0;
#pragma unroll
    for (int dd = 0; dd < 4; dd++) {
      unsigned long long m = __ballot(d == dd);
      if (d == dd) pos = pstA[dd] + preL[dd] + (int)__popcll(m & ltm);
    }
    posL[lane] = pos;
    perm[pos] = row;
  }
  __syncthreads();
  for (int i = 0; i < 4; i++) {
    int ridx = wv * 4 + i;
    int r = B * 16 + ridx;
    const float* xr = x + (size_t)r * DIN;
    float4 v[4];
#pragma unroll
    for (int g = 0; g < 4; g++) v[g] = *(const float4*)(xr + g * 256 + lane * 4);
    float s = 0.f;
#pragma unroll
    for (int g = 0; g < 4; g++) s += v[g].x + v[g].y + v[g].z + v[g].w;
#pragma unroll
    for (int o = 32; o; o >>= 1) s += __shfl_xor(s, o, 64);
    float mean = s * (1.f / 1024.f);
    float q = 0.f;
#pragma unroll
    for (int g = 0; g < 4; g++) {
      float a = v[g].x - mean, b = v[g].y - mean, c = v[g].z - mean, e = v[g].w - mean;
      q += a * a + b * b + c * c + e * e;
    }
#pragma unroll
    for (int o = 32; o; o >>= 1) q += __shfl_xor(q, o, 64);
    float rstd = rsqrtf(q * (1.f / 1024.f) + 1e-5f);
    int d = dom[r];
    int pos = posL[ridx];
    const float* pw = pn_w + (size_t)d * DIN;
    const float* pb = pn_b + (size_t)d * DIN;
    u8* orow = norm + (size_t)pos * DIN;
#pragma unroll
    for (int g = 0; g < 4; g++) {
      float4 w4 = *(const float4*)(pw + g * 256 + lane * 4);
      float4 b4 = *(const float4*)(pb + g * 256 + lane * 4);
      float f0 = (v[g].x - mean) * rstd * w4.x + b4.x;
      float f1 = (v[g].y - mean) * rstd * w4.y + b4.y;
      float f2 = (v[g].z - mean) * rstd * w4.z + b4.z;
      float f3 = (v[g].w - mean) * rstd * w4.w + b4.w;
      int u = __builtin_amdgcn_cvt_pk_fp8_f32(f0, f1, 0, false);
      u = __builtin_amdgcn_cvt_pk_fp8_f32(f2, f3, u, true);
      *(unsigned int*)(orow + g * 256 + lane * 4) = (unsigned int)u;
    }
  }
}

// ------------------------------------------------ fused center|domain fp8 GEMM (L1, L2)
// M-tile 64, N-tile 128, BK 128. b128 LDS reads via K-permutation; LDS slot c of
// row r holds global 16B chunk c^(r&7) (xor swizzle, bank-free). [R8-proven best:
// 52 VGPR -> ~27% occupancy is the latency-hiding sweet spot; N256 (104 VGPR,
// 13.5% occ) regressed 8 µs — wave-level overlap is what masks the barrier drain]
__global__ __launch_bounds__(256) void k_gemm(const u8* __restrict__ A, int lda,
                                              int aoffc, int aoffd,
                                              const u8* __restrict__ cWt,
                                              const u8* __restrict__ dWt,
                                              const float* __restrict__ cb,
                                              const float* __restrict__ db,
                                              u8* __restrict__ C, int Nh, int Kd,
                                              int relu, const int* __restrict__ pstart,
                                              int lognct) {
  __shared__ __align__(16) u8 Al[64 * 128];    // 8 KB
  __shared__ __align__(16) u8 Bl[128 * 128];   // 16 KB
  const int tid = threadIdx.x;
  const int wv = tid >> 6, lane = tid & 63;
  const int nct = 1 << lognct;
  // XCD swizzle: col-tiles of one row-tile share l&7 -> same XCD L2.
  int l = blockIdx.x;
  int t = l >> 3;
  int ct = t & (nct - 1);
  int rt = ((t >> lognct) << 3) | (l & 7);   // 264 row-tiles, 264%8==0
  const int row0 = rt * 64;
  const int d = (row0 >= pstart[1]) + (row0 >= pstart[2]) + (row0 >= pstart[3]);
  const int n0 = ct * 128;
  const bool isd = (n0 >= Nh);
  const u8* Wt = isd ? dWt + ((size_t)d * Nh + (n0 - Nh)) * Kd : cWt + (size_t)n0 * Kd;
  const float* bias = isd ? db + d * Nh + (n0 - Nh) : cb + n0;
  const int aoff = isd ? aoffd : aoffc;
  const u8* Ab = A + (size_t)row0 * lda + aoff;

  v4f acc[2][4];
#pragma unroll
  for (int i = 0; i < 2; i++)
#pragma unroll
    for (int j = 0; j < 4; j++) acc[i][j] = v4f{0.f, 0.f, 0.f, 0.f};

  const int wm = (wv >> 1) * 32, wn = (wv & 1) * 64;
  const int mrow = lane & 15, quad = lane >> 4;
  const int lrow = lane >> 3;   // loader: 8 rows per instr
  const int lchk = lane & 7;    // loader: 8 chunks of 16B per row
  const int ldc = 2 * Nh;

  for (int kt = 0; kt < Kd; kt += 128) {
#pragma unroll
    for (int p = 0; p < 2; p++) {          // A: wave rows [wv*16, +16)
      int rbase = wv * 16 + p * 8;
      int r = rbase + lrow;
      int jg = lchk ^ (r & 7);
      gl_lds16(Ab + (size_t)r * lda + kt + jg * 16, &Al[rbase * 128]);
    }
#pragma unroll
    for (int p = 0; p < 4; p++) {          // B: wave rows [wv*32, +32)
      int rbase = wv * 32 + p * 8;
      int r = rbase + lrow;
      int jg = lchk ^ (r & 7);
      gl_lds16(Wt + (size_t)r * Kd + kt + jg * 16, &Bl[rbase * 128]);
    }
    __syncthreads();
#pragma unroll
    for (int sp = 0; sp < 2; sp++) {
      v2l af[2], bfr[4];
#pragma unroll
      for (int mi = 0; mi < 2; mi++) {
        int m = wm + mi * 16 + mrow;
        int c = (sp * 4 + quad) ^ (m & 7);
        af[mi] = *(const v2l*)&Al[m * 128 + c * 16];
      }
#pragma unroll
      for (int ni = 0; ni < 4; ni++) {
        int n = wn + ni * 16 + mrow;
        int c = (sp * 4 + quad) ^ (n & 7);
        bfr[ni] = *(const v2l*)&Bl[n * 128 + c * 16];
      }
#pragma unroll
      for (int mi = 0; mi < 2; mi++)
#pragma unroll
        for (int ni = 0; ni < 4; ni++)
          acc[mi][ni] =
              __builtin_amdgcn_mfma_f32_16x16x32_fp8_fp8(af[mi].x, bfr[ni].x, acc[mi][ni], 0, 0, 0);
#pragma unroll
      for (int mi = 0; mi < 2; mi++)
#pragma unroll
        for (int ni = 0; ni < 4; ni++)
          acc[mi][ni] =
              __builtin_amdgcn_mfma_f32_16x16x32_fp8_fp8(af[mi].y, bfr[ni].y, acc[mi][ni], 0, 0, 0);
    }
    __syncthreads();
  }

  float bv[4];
#pragma unroll
  for (int ni = 0; ni < 4; ni++) bv[ni] = bias[wn + ni * 16 + mrow];
#pragma unroll
  for (int mi = 0; mi < 2; mi++) {
    int growb = row0 + wm + mi * 16 + quad * 4;
#pragma unroll
    for (int ni = 0; ni < 4; ni++) {
      int gcol = n0 + wn + ni * 16 + mrow;
#pragma unroll
      for (int r2 = 0; r2 < 4; r2++) {
        float v = acc[mi][ni][r2] * 0.0625f + bv[ni];
        if (relu) v = fmaxf(v, 0.f);
        float g = __shfl_xor(v, 1, 64);
        if (!(mrow & 1))
          *(unsigned short*)(C + (size_t)(growb + r2) * ldc + gcol) = pk8(v, g);
      }
    }
  }
}

// ------------------------------------------------ L3 fp8 GEMM + bf16 MFMA head [R5-proven]
__global__ __launch_bounds__(256) void k_gemm3(const u8* __restrict__ A,
                                               const u8* __restrict__ cW3t,
                                               const u8* __restrict__ dW3t,
                                               const float* __restrict__ cb3,
                                               const float* __restrict__ db3,
                                               const bf16* __restrict__ fW1t,
                                               const float* __restrict__ fb1,
                                               const float* __restrict__ fW2,
                                               const float* __restrict__ fb2,
                                               const int* __restrict__ perm,
                                               const int* __restrict__ pstart,
                                               const float* __restrict__ aux,
                                               float* __restrict__ out) {
  __shared__ __align__(16) u8 Al[64 * 128];        // 8 KB
  __shared__ __align__(16) u8 Bl[128 * 128];       // 16 KB
  __shared__ __align__(16) bf16 fusedL[64 * 128];  // 16 KB, XOR-swizzled 8-elt chunks
  __shared__ __align__(16) bf16 fwB[64 * 128];     // 16 KB, XOR-swizzled 8-elt chunks
  const int tid = threadIdx.x, wv = tid >> 6, lane = tid & 63;
  const int row0 = blockIdx.x * 64;
  const int d = (row0 >= pstart[1]) + (row0 >= pstart[2]) + (row0 >= pstart[3]);
  const u8* Ab = A + (size_t)row0 * 512;
  const int mrow = lane & 15, quad = lane >> 4;
  const int lrow = lane >> 3, lchk = lane & 7;
  const int wm = (wv >> 1) * 32, wn = (wv & 1) * 64;

  {
    int c = lane & 15, rsub = lane >> 4;
#pragma unroll
    for (int p = 0; p < 4; p++) {
      int rbase = wv * 16 + p * 4;
      int row = rbase + rsub;
      int g = (c & 8) | ((c ^ row) & 7);
      gl_lds16(fW1t + row * 128 + g * 8, &fwB[rbase * 128]);
    }
  }

  v4f accC[2][4], accD[2][4];
#pragma unroll
  for (int i = 0; i < 2; i++)
#pragma unroll
    for (int j = 0; j < 4; j++) { accC[i][j] = v4f{0.f,0.f,0.f,0.f}; accD[i][j] = v4f{0.f,0.f,0.f,0.f}; }

#pragma unroll
  for (int ph = 0; ph < 2; ph++) {
    const u8* Wt = ph ? dW3t + (size_t)d * 32768 : cW3t;
    const int aoff = ph * 256;
    for (int kt = 0; kt < 256; kt += 128) {
#pragma unroll
      for (int p = 0; p < 2; p++) {        // A: 64 rows
        int rbase = wv * 16 + p * 8;
        int r = rbase + lrow;
        int jg = lchk ^ (r & 7);
        gl_lds16(Ab + (size_t)r * 512 + aoff + kt + jg * 16, &Al[rbase * 128]);
      }
#pragma unroll
      for (int p = 0; p < 4; p++) {        // B: 128 rows
        int rbase = wv * 32 + p * 8;
        int r = rbase + lrow;
        int jg = lchk ^ (r & 7);
        gl_lds16(Wt + (size_t)r * 256 + kt + jg * 16, &Bl[rbase * 128]);
      }
      __syncthreads();
#pragma unroll
      for (int sp = 0; sp < 2; sp++) {
        v2l af[2], bfr[4];
#pragma unroll
        for (int mi = 0; mi < 2; mi++) {
          int m = wm + mi * 16 + mrow;
          int c = (sp * 4 + quad) ^ (m & 7);
          af[mi] = *(const v2l*)&Al[m * 128 + c * 16];
        }
#pragma unroll
        for (int ni = 0; ni < 4; ni++) {
          int n = wn + ni * 16 + mrow;
          int c = (sp * 4 + quad) ^ (n & 7);
          bfr[ni] = *(const v2l*)&Bl[n * 128 + c * 16];
        }
        if (ph == 0) {
#pragma unroll
          for (int mi = 0; mi < 2; mi++)
#pragma unroll
            for (int ni = 0; ni < 4; ni++) {
              accC[mi][ni] = __builtin_amdgcn_mfma_f32_16x16x32_fp8_fp8(af[mi].x, bfr[ni].x, accC[mi][ni], 0, 0, 0);
              accC[mi][ni] = __builtin_amdgcn_mfma_f32_16x16x32_fp8_fp8(af[mi].y, bfr[ni].y, accC[mi][ni], 0, 0, 0);
            }
        } else {
#pragma unroll
          for (int mi = 0; mi < 2; mi++)
#pragma unroll
            for (int ni = 0; ni < 4; ni++) {
              accD[mi][ni] = __builtin_amdgcn_mfma_f32_16x16x32_fp8_fp8(af[mi].x, bfr[ni].x, accD[mi][ni], 0, 0, 0);
              accD[mi][ni] = __builtin_amdgcn_mfma_f32_16x16x32_fp8_fp8(af[mi].y, bfr[ni].y, accD[mi][ni], 0, 0, 0);
            }
        }
      }
      __syncthreads();
    }
  }

#pragma unroll
  for (int mi = 0; mi < 2; mi++) {
    int rowb = wm + mi * 16 + quad * 4;
#pragma unroll
    for (int ni = 0; ni < 4; ni++) {
      int col = wn + ni * 16 + mrow;
      float cbv = cb3[col];
      float dbv = db3[d * 128 + col];
      int jc = col >> 3, coff = col & 7;
#pragma unroll
      for (int r2 = 0; r2 < 4; r2++) {
        int rr = rowb + r2;
        float f = (accC[mi][ni][r2] * 0.0625f + cbv) * tanhf(accD[mi][ni][r2] * 0.0625f + dbv);
        int cs = (jc & 8) | ((jc ^ rr) & 7);
        fusedL[rr * 128 + cs * 8 + coff] = (bf16)f;
      }
    }
  }
  __syncthreads();

  float fb1v[4], fW2v[4];
#pragma unroll
  for (int nt = 0; nt < 4; nt++) {
    int col = nt * 16 + mrow;
    fb1v[nt] = fb1[col];
    fW2v[nt] = fW2[col];
  }
  v4f hacc[4];
#pragma unroll
  for (int nt = 0; nt < 4; nt++) hacc[nt] = v4f{0.f, 0.f, 0.f, 0.f};
  const int m = wv * 16 + mrow;
#pragma unroll
  for (int s = 0; s < 4; s++) {
    int j = s * 4 + quad;
    int ca = (j & 8) | ((j ^ m) & 7);
    v8bf af = *(const v8bf*)&fusedL[m * 128 + ca * 8];
#pragma unroll
    for (int nt = 0; nt < 4; nt++) {
      int n = nt * 16 + mrow;
      int cbk = (j & 8) | ((j ^ n) & 7);
      v8bf bfr = *(const v8bf*)&fwB[n * 128 + cbk * 8];
      hacc[nt] = __builtin_amdgcn_mfma_f32_16x16x32_bf16(af, bfr, hacc[nt], 0, 0, 0);
    }
  }
  float ys[4];
#pragma unroll
  for (int r2 = 0; r2 < 4; r2++) {
    float s = 0.f;
#pragma unroll
    for (int nt = 0; nt < 4; nt++) s += fmaxf(hacc[nt][r2] + fb1v[nt], 0.f) * fW2v[nt];
    ys[r2] = s;
  }
#pragma unroll
  for (int o = 1; o < 16; o <<= 1)
#pragma unroll
    for (int r2 = 0; r2 < 4; r2++) ys[r2] += __shfl_xor(ys[r2], o, 64);
  if (mrow == 0) {
    const float addc = fb2[0] + aux[d];
#pragma unroll
    for (int r2 = 0; r2 < 4; r2++) {
      int prow = row0 + wv * 16 + quad * 4 + r2;
      int orig = perm[prow];
      if (orig >= 0) out[orig] = 1.f / (1.f + expf(-(ys[r2] + addc)));
    }
  }
}

// ------------------------------------------------ launch
extern "C" void kernel_launch(void* const* d_in, const int* in_sizes, int n_in,
                              void* d_out, int out_size, void* d_ws, size_t ws_size,
                              hipStream_t stream) {
  (void)in_sizes; (void)n_in; (void)out_size; (void)ws_size;
  const float* x      = (const float*)d_in[0];
  const int*   dom    = (const int*)d_in[1];
  const float* pn_w   = (const float*)d_in[2];
  const float* pn_b   = (const float*)d_in[3];
  const float* cW1    = (const float*)d_in[4];
  const float* cb1    = (const float*)d_in[5];
  const float* cW2    = (const float*)d_in[6];
  const float* cb2    = (const float*)d_in[7];
  const float* cW3    = (const float*)d_in[8];
  const float* cb3    = (const float*)d_in[9];
  const float* dW1    = (const float*)d_in[10];
  const float* db1    = (const float*)d_in[11];
  const float* dW2    = (const float*)d_in[12];
  const float* db2    = (const float*)d_in[13];
  const float* dW3    = (const float*)d_in[14];
  const float* db3    = (const float*)d_in[15];
  const float* fW1    = (const float*)d_in[16];
  const float* fb1    = (const float*)d_in[17];
  const float* fW2    = (const float*)d_in[18];
  const float* fb2    = (const float*)d_in[19];
  const float* demb   = (const float*)d_in[20];
  const float* aW1    = (const float*)d_in[21];
  const float* ab1    = (const float*)d_in[22];
  const float* aW2    = (const float*)d_in[23];
  const float* ab2    = (const float*)d_in[24];
  float* out = (float*)d_out;

  char* w = (char*)d_ws;
  int*   pstart  = (int*)(w + 32);      // [5]
  float* aux     = (float*)(w + 64);    // [4]
  int*   perm    = (int*)(w + 256);                    // [MPAD] -> 67840
  int*   partials= (int*)(w + 67840);                  // [1024*4] -> 84224
  u8*    bufA    = (u8*)(w + 133376);                  // norm MPADx1024 fp8, then h2 MPADx512
  u8*    bufB    = (u8*)(w + 17434880);                // h1 MPADx1024 fp8
  u8*    cW1t    = (u8*)(w + 34736384);
  u8*    cW2t    = (u8*)(w + 35260672);
  u8*    cW3t    = (u8*)(w + 35391744);
  u8*    dW1t    = (u8*)(w + 35424512);
  u8*    dW2t    = (u8*)(w + 37521664);
  u8*    dW3t    = (u8*)(w + 38045952);
  bf16*  fW1t    = (bf16*)(w + 38177024);              // 64x128 bf16 -> end 38193408

  // prep: weight transpose + hist partials + perm init + aux
  k_prep<<<906, 256, 0, stream>>>(cW1, cW2, cW3, dW1, dW2, dW3, fW1,
                                  cW1t, cW2t, cW3t, dW1t, dW2t, dW3t, fW1t,
                                  dom, partials, perm,
                                  demb, aW1, ab1, aW2, ab2, aux);
  // sort + layernorm fused
  k_sortln<<<1024, 256, 0, stream>>>(x, dom, partials, pn_w, pn_b,
                                     pstart, perm, bufA);

  // L1: norm(bufA) -> h1(bufB) : K=1024, Nh=512, relu, 8 col tiles, 264 row tiles
  k_gemm<<<2112, 256, 0, stream>>>(bufA, 1024, 0, 0, cW1t, dW1t, cb1, db1,
                                   bufB, 512, 1024, 1, pstart, 3);
  // L2: h1(bufB) -> h2(bufA) : K=512, Nh=256, relu, 4 col tiles
  k_gemm<<<1056, 256, 0, stream>>>(bufB, 1024, 0, 512, cW2t, dW2t, cb2, db2,
                                   bufA, 256, 512, 1, pstart, 2);
  // L3 + head fused: h2(bufA) -> out
  k_gemm3<<<264, 256, 0, stream>>>(bufA, cW3t, dW3t, cb3, db3, fW1t,
                                   fb1, fW2, fb2, perm, pstart, aux, out);
}